// Round 1
// 133.120 us; speedup vs baseline: 1.0063x; 1.0063x over previous
//
#include <hip/hip_runtime.h>
#include <math.h>

#define DK 32
#define OUT_DIM 32

typedef float    f32x4 __attribute__((ext_vector_type(4)));
typedef _Float16 h2    __attribute__((ext_vector_type(2)));
typedef _Float16 h8    __attribute__((ext_vector_type(8)));

#if __has_builtin(__builtin_amdgcn_fdot2)
#define FDOT2(a, b, c) __builtin_amdgcn_fdot2((a), (b), (c), false)
#else
#define FDOT2(a, b, c) ((c) + (float)(a).x * (float)(b).x + (float)(a).y * (float)(b).y)
#endif

__device__ __forceinline__ h2 as_h2(unsigned u) {
    union { unsigned u; h2 h; } v; v.u = u; return v.h;
}
__device__ __forceinline__ unsigned as_u32(h2 h) {
    union { unsigned u; h2 h; } v; v.h = h; return v.u;
}
__device__ __forceinline__ h2 shfl_xor_h2(h2 v, int m) {
    union { unsigned u; h2 h; } x; x.h = v;
    x.u = (unsigned)__shfl_xor((int)x.u, m);
    return x.h;
}

// R12 prep: vectorized. One thread per (node, chunk) = N*8 threads; two
// coalesced float4 loads (K,V) -> four f16 pairs -> one uint4 store.
// KVH row layout per node: 8 uint4, chunk c = {K01,K23,V01,V23} for dims
// 4c..4c+3 (identical layout/numerics to R11, 4x fewer VMEM instrs).
// Also fuses row_ptr boundary detection on sorted dst (unchanged).
__global__ void prep_kernel(const int* __restrict__ dst,
                            const float4* __restrict__ K4,
                            const float4* __restrict__ V4,
                            int E, int N,
                            int* __restrict__ row_ptr,
                            uint4* __restrict__ KVH) {
    const int t = blockIdx.x * blockDim.x + threadIdx.x;
    if (t < E) {
        const int cur  = dst[t];
        const int prev = (t == 0) ? -1 : dst[t - 1];
        for (int j = prev + 1; j <= cur; ++j) row_ptr[j] = t;
        if (t == E - 1) {
            for (int j = cur + 1; j <= N; ++j) row_ptr[j] = E;
        }
    }
    if (t < N * 8) {
        const float4 kf = K4[t];   // K[s][4c..4c+3]
        const float4 vf = V4[t];   // V[s][4c..4c+3]
        h2 k01, k23, v01, v23;
        k01.x = (_Float16)kf.x;  k01.y = (_Float16)kf.y;
        k23.x = (_Float16)kf.z;  k23.y = (_Float16)kf.w;
        v01.x = (_Float16)vf.x;  v01.y = (_Float16)vf.y;
        v23.x = (_Float16)vf.z;  v23.y = (_Float16)vf.w;
        uint4 o;
        o.x = as_u32(k01); o.y = as_u32(k23); o.z = as_u32(v01); o.w = as_u32(v23);
        KVH[t] = o;
    }
}

// Fallback-path row_ptr builder (ws too small for KV).
__global__ void build_row_ptr_kernel(const int* __restrict__ dst, int E, int N,
                                     int* __restrict__ row_ptr) {
    int e = blockIdx.x * blockDim.x + threadIdx.x;
    if (e >= E) return;
    int cur  = dst[e];
    int prev = (e == 0) ? -1 : dst[e - 1];
    for (int j = prev + 1; j <= cur; ++j) row_ptr[j] = e;
    if (e == E - 1) {
        for (int j = cur + 1; j <= N; ++j) row_ptr[j] = E;
    }
}

// R12 = R11 + 2-deep software pipeline in the edge loop.
// Theory: the loop is latency-bound on the serial src[e] -> KV[src] gather
// chain (~700cy exposed) with only ~4 waves/SIMD of TLP. Ping-pong buffers
// (P/Q) issue batch i+1's 4 KV gathers BEFORE batch i's compute, with the
// needed src indices prefetched one batch earlier, so the gather latency
// overlaps the dot/softmax/accumulate work. All prefetches are guarded by
// wave-uniform scalar branches (more/more2), so 1-batch segments issue
// exactly R11's load count (no wasted VMEM on tails). Math identical to
// R11: f16 dot2 + pk_fma, masked exp, block A-tile + 8 f16 MFMA epilogue.
__global__ __launch_bounds__(256) void gat_fused_kernel(
    const float* __restrict__ X, const uint4* __restrict__ KV,
    const float* __restrict__ Wo, const float* __restrict__ bo,
    const int* __restrict__ src, const int* __restrict__ row_ptr,
    float* __restrict__ out, int N) {

    __shared__ uint4 s_part[16 * 17];   // block A-tile, row stride 17 (pad->b128)

    const int tid  = threadIdx.x;
    const int w    = tid >> 6;    // wave 0..3
    const int lane = tid & 63;
    const int g    = lane >> 3;   // edge slot 0..7
    const int c    = lane & 7;    // dim chunk 0..7

    const int n_blk = blockIdx.x * 16;       // block's first node (< N always)
    const int n_w   = n_blk + w * 4;         // wave's first node

    // row_ptr[n_w .. n_w+4] into lanes 0..4 (clamped; row_ptr[N] = E)
    const int rpv = row_ptr[min(n_w + min(lane, 4), N)];

    const float4* X4 = (const float4*)X;
    unsigned* part32 = (unsigned*)s_part;
    const float scale = 0.03125f;

    for (int pr = 0; pr < 2; ++pr) {
        const int ia = pr * 2;
        const int beginA = __builtin_amdgcn_readlane(rpv, ia);
        const int endA   = __builtin_amdgcn_readlane(rpv, ia + 1);
        const int endB   = __builtin_amdgcn_readlane(rpv, ia + 2);
        const int beginB = endA;
        const int nA = n_w + ia;             // may be >= N in last block
        const int nB = nA + 1;

        float4 qa = X4[min(nA, N - 1) * 8 + c];
        float4 qb = X4[min(nB, N - 1) * 8 + c];
        h2 qa01, qa23, qb01, qb23;           // scaled q as f16 pairs
        qa01.x = (_Float16)(qa.x * scale);  qa01.y = (_Float16)(qa.y * scale);
        qa23.x = (_Float16)(qa.z * scale);  qa23.y = (_Float16)(qa.w * scale);
        qb01.x = (_Float16)(qb.x * scale);  qb01.y = (_Float16)(qb.y * scale);
        qb23.x = (_Float16)(qb.z * scale);  qb23.y = (_Float16)(qb.w * scale);

        float lA = 0.0f, lB = 0.0f;
        h2 aA01 = (h2)0, aA23 = (h2)0, aB01 = (h2)0, aB23 = (h2)0;

        const int capA = max(endA - 1, 0);   // safe clamp (empty -> idx 0)
        const int capB = max(endB - 1, 0);
        int eA = beginA, eB = beginB;

        // One 32-slot batch: dots, group-reduce, masked exp, V accumulate.
        // Masks use the CURRENT (pre-increment) eA/eB via reference capture.
        auto step = [&](const uint4& A0, const uint4& A1,
                        const uint4& B0, const uint4& B1) {
            float p0 = FDOT2(as_h2(A0.y), qa23, FDOT2(as_h2(A0.x), qa01, 0.0f));
            float p1 = FDOT2(as_h2(A1.y), qa23, FDOT2(as_h2(A1.x), qa01, 0.0f));
            float p2 = FDOT2(as_h2(B0.y), qb23, FDOT2(as_h2(B0.x), qb01, 0.0f));
            float p3 = FDOT2(as_h2(B1.y), qb23, FDOT2(as_h2(B1.x), qb01, 0.0f));
            p0 += __shfl_xor(p0, 1);  p1 += __shfl_xor(p1, 1);
            p2 += __shfl_xor(p2, 1);  p3 += __shfl_xor(p3, 1);
            p0 += __shfl_xor(p0, 2);  p1 += __shfl_xor(p1, 2);
            p2 += __shfl_xor(p2, 2);  p3 += __shfl_xor(p3, 2);
            p0 += __shfl_xor(p0, 4);  p1 += __shfl_xor(p1, 4);
            p2 += __shfl_xor(p2, 4);  p3 += __shfl_xor(p3, 4);

            const float w0 = (eA + g     < endA) ? __expf(p0) : 0.0f;
            const float w1 = (eA + 8 + g < endA) ? __expf(p1) : 0.0f;
            const float w2 = (eB + g     < endB) ? __expf(p2) : 0.0f;
            const float w3 = (eB + 8 + g < endB) ? __expf(p3) : 0.0f;
            lA += w0 + w1;
            lB += w2 + w3;

            h2 wh0; wh0.x = (_Float16)w0; wh0.y = wh0.x;
            h2 wh1; wh1.x = (_Float16)w1; wh1.y = wh1.x;
            h2 wh2; wh2.x = (_Float16)w2; wh2.y = wh2.x;
            h2 wh3; wh3.x = (_Float16)w3; wh3.y = wh3.x;
            aA01 += wh0 * as_h2(A0.z);  aA23 += wh0 * as_h2(A0.w);
            aA01 += wh1 * as_h2(A1.z);  aA23 += wh1 * as_h2(A1.w);
            aB01 += wh2 * as_h2(B0.z);  aB23 += wh2 * as_h2(B0.w);
            aB01 += wh3 * as_h2(B1.z);  aB23 += wh3 * as_h2(B1.w);
        };

        if (eA < endA || eB < endB) {
            // ---- prologue: src(0) -> KV(0) issue, then src(1) prefetch ----
            int sp0 = src[min(eA + g,     capA)];
            int sp1 = src[min(eA + 8 + g, capA)];
            int sp2 = src[min(eB + g,     capB)];
            int sp3 = src[min(eB + 8 + g, capB)];
            uint4 P0 = KV[sp0 * 8 + c];
            uint4 P1 = KV[sp1 * 8 + c];
            uint4 P2 = KV[sp2 * 8 + c];
            uint4 P3 = KV[sp3 * 8 + c];
            int sq0 = 0, sq1 = 0, sq2 = 0, sq3 = 0;
            uint4 Q0, Q1, Q2, Q3;
            bool more = (eA + 16 < endA) || (eB + 16 < endB);  // batch @+16?
            if (more) {
                sq0 = src[min(eA + 16 + g, capA)];
                sq1 = src[min(eA + 24 + g, capA)];
                sq2 = src[min(eB + 16 + g, capB)];
                sq3 = src[min(eB + 24 + g, capB)];
            }
            for (;;) {
                // ---- half X: consume P @ (eA,eB); sq = src for +16 ----
                bool more2 = false;
                if (more) {
                    Q0 = KV[sq0 * 8 + c];        // issue next KV before compute
                    Q1 = KV[sq1 * 8 + c];
                    Q2 = KV[sq2 * 8 + c];
                    Q3 = KV[sq3 * 8 + c];
                    more2 = (eA + 32 < endA) || (eB + 32 < endB);
                    if (more2) {                 // prefetch src two ahead
                        sp0 = src[min(eA + 32 + g, capA)];
                        sp1 = src[min(eA + 40 + g, capA)];
                        sp2 = src[min(eB + 32 + g, capB)];
                        sp3 = src[min(eB + 40 + g, capB)];
                    }
                }
                step(P0, P1, P2, P3);
                eA += 16; eB += 16;
                if (!more) break;

                // ---- half Y: consume Q; sp = src for +16 (iff more2) ----
                bool more3 = false;
                if (more2) {
                    P0 = KV[sp0 * 8 + c];
                    P1 = KV[sp1 * 8 + c];
                    P2 = KV[sp2 * 8 + c];
                    P3 = KV[sp3 * 8 + c];
                    more3 = (eA + 32 < endA) || (eB + 32 < endB);
                    if (more3) {
                        sq0 = src[min(eA + 32 + g, capA)];
                        sq1 = src[min(eA + 40 + g, capA)];
                        sq2 = src[min(eB + 32 + g, capB)];
                        sq3 = src[min(eB + 40 + g, capB)];
                    }
                }
                step(Q0, Q1, Q2, Q3);
                eA += 16; eB += 16;
                if (!more2) break;
                more = more3;
            }
        }

        // ---- per-node reductions + A-tile writes (A then B) ----
        lA   += __shfl_xor(lA, 8);
        aA01 += shfl_xor_h2(aA01, 8);
        aA23 += shfl_xor_h2(aA23, 8);
        lA += __shfl_xor(lA, 16);  lA += __shfl_xor(lA, 32);

        lB   += __shfl_xor(lB, 8);
        aB01 += shfl_xor_h2(aB01, 8);
        aB23 += shfl_xor_h2(aB23, 8);
        lB += __shfl_xor(lB, 16);  lB += __shfl_xor(lB, 32);

        const float invA = (endA > beginA) ? (1.0f / lA) : 0.0f;
        const float invB = (endB > beginB) ? (1.0f / lB) : 0.0f;
        h2 ivA; ivA.x = (_Float16)invA; ivA.y = ivA.x;
        h2 ivB; ivB.x = (_Float16)invB; ivB.y = ivB.x;
        aA01 *= ivA;  aA23 *= ivA;
        aB01 *= ivB;  aB23 *= ivB;

        if ((g & 1) == 0) {                  // even groups hold pair sums
            const int p   = g >> 1;
            const int row = w * 4 + ia;
            int off = row * 68 + p * 16 + c * 2;   // uint32 units
            part32[off]     = as_u32(aA01);
            part32[off + 1] = as_u32(aA23);
            off += 68;
            part32[off]     = as_u32(aB01);
            part32[off + 1] = as_u32(aB23);
        }
    }

    __syncthreads();

    // wave 0: projection + partial-group reduction for the block's 16 nodes
    if (w == 0) {
        const int quad = lane >> 4;   // 0..3
        const int col  = lane & 15;

        union BF { h8 v; _Float16 u[8]; };
        BF bf0, bf1;
#pragma unroll
        for (int j2 = 0; j2 < 8; ++j2) {
            bf0.u[j2] = (_Float16)Wo[(quad * 8 + j2) * OUT_DIM + col];
            bf1.u[j2] = (_Float16)Wo[(quad * 8 + j2) * OUT_DIM + 16 + col];
        }
        const float bias0 = bo[col];
        const float bias1 = bo[16 + col];

        union AF { uint4 u; h8 v; };
        f32x4 C0 = {bias0, bias0, bias0, bias0};
        f32x4 C1 = {bias1, bias1, bias1, bias1};
#pragma unroll
        for (int cc = 0; cc < 4; ++cc) {
            AF a;
            a.u = s_part[col * 17 + cc * 4 + quad];      // ds_read_b128
            C0 = __builtin_amdgcn_mfma_f32_16x16x32_f16(a.v, bf0.v, C0, 0, 0, 0);
            C1 = __builtin_amdgcn_mfma_f32_16x16x32_f16(a.v, bf1.v, C1, 0, 0, 0);
        }
        // C/D layout: col = lane&15, row = quad*4 + reg (verified mapping)
#pragma unroll
        for (int r = 0; r < 4; ++r) {
            const int n = n_blk + quad * 4 + r;
            if (n < N) {
                out[n * OUT_DIM + col]      = C0[r];
                out[n * OUT_DIM + 16 + col] = C1[r];
            }
        }
    }
}

// ---- fallback (R4-proven fp32 path, used only if ws too small for KV) ----
__global__ __launch_bounds__(256) void gat_node_f32_kernel(
    const float* __restrict__ X, const float* __restrict__ Km,
    const float* __restrict__ Vm, const float* __restrict__ Wo,
    const float* __restrict__ bo, const int* __restrict__ src,
    const int* __restrict__ row_ptr, float* __restrict__ out, int N) {
    const int tid  = threadIdx.x;
    const int wave = tid >> 6;
    const int lane = tid & 63;
    const int g    = lane >> 3;
    const int c    = lane & 7;
    const int j    = lane & 31;
    const int half = lane >> 5;
    const int n = blockIdx.x * 4 + wave;
    if (n >= N) return;
    const int begin = row_ptr[n];
    const int end   = row_ptr[n + 1];
    const float4* X4 = (const float4*)X;
    const float4* K4 = (const float4*)Km;
    const float4* V4 = (const float4*)Vm;
    const float4 q4 = X4[n * 8 + c];
    float  l   = 0.0f;
    float4 acc = make_float4(0.0f, 0.0f, 0.0f, 0.0f);
    for (int e0 = begin; e0 < end; e0 += 16) {
        const int  ea = e0 + g;
        const int  eb = ea + 8;
        const bool va = ea < end;
        const bool vb = eb < end;
        const int sa = src[min(ea, end - 1)];
        const int sb = src[min(eb, end - 1)];
        const float4 ka  = K4[sa * 8 + c];
        const float4 kb  = K4[sb * 8 + c];
        const float4 vva = V4[sa * 8 + c];
        const float4 vvb = V4[sb * 8 + c];
        float pa = fmaf(ka.x, q4.x, fmaf(ka.y, q4.y, fmaf(ka.z, q4.z, ka.w * q4.w)));
        float pb = fmaf(kb.x, q4.x, fmaf(kb.y, q4.y, fmaf(kb.z, q4.z, kb.w * q4.w)));
        pa += __shfl_xor(pa, 1);  pb += __shfl_xor(pb, 1);
        pa += __shfl_xor(pa, 2);  pb += __shfl_xor(pb, 2);
        pa += __shfl_xor(pa, 4);  pb += __shfl_xor(pb, 4);
        const float wa = va ? __expf(pa * 0.03125f) : 0.0f;
        const float wb = vb ? __expf(pb * 0.03125f) : 0.0f;
        l += wa + wb;
        acc.x = fmaf(wa, vva.x, acc.x);  acc.y = fmaf(wa, vva.y, acc.y);
        acc.z = fmaf(wa, vva.z, acc.z);  acc.w = fmaf(wa, vva.w, acc.w);
        acc.x = fmaf(wb, vvb.x, acc.x);  acc.y = fmaf(wb, vvb.y, acc.y);
        acc.z = fmaf(wb, vvb.z, acc.z);  acc.w = fmaf(wb, vvb.w, acc.w);
    }
#pragma unroll
    for (int m = 8; m <= 32; m <<= 1) {
        l     += __shfl_xor(l, m);
        acc.x += __shfl_xor(acc.x, m);
        acc.y += __shfl_xor(acc.y, m);
        acc.z += __shfl_xor(acc.z, m);
        acc.w += __shfl_xor(acc.w, m);
    }
    const float inv = (end > begin) ? (1.0f / l) : 0.0f;
    float ag[4] = {acc.x, acc.y, acc.z, acc.w};
    float s = 0.0f;
#pragma unroll
    for (int k = 0; k < 32; ++k) {
        const float a = __int_as_float(
            __builtin_amdgcn_readlane(__float_as_int(ag[k & 3]), k >> 2));
        s = fmaf(a, Wo[k * OUT_DIM + j], s);
    }
    if (half == 0) {
        out[n * OUT_DIM + j] = fmaf(s, inv, bo[j]);
    }
}

extern "C" void kernel_launch(void* const* d_in, const int* in_sizes, int n_in,
                              void* d_out, int out_size, void* d_ws, size_t ws_size,
                              hipStream_t stream) {
    const float* X  = (const float*)d_in[0];
    const float* Km = (const float*)d_in[1];
    const float* Vm = (const float*)d_in[2];
    const float* Wo = (const float*)d_in[3];
    const float* bo = (const float*)d_in[4];
    const int* src  = (const int*)d_in[5];
    const int* dst  = (const int*)d_in[6];

    const int N = in_sizes[0] / DK;
    const int E = in_sizes[5];

    int* row_ptr = (int*)d_ws;                              // (N+1) ints
    const size_t kv_off = (((size_t)(N + 1) * 4) + 127) & ~(size_t)127;
    unsigned* KV = (unsigned*)((char*)d_ws + kv_off);       // N*DK uint32
    const size_t need = kv_off + (size_t)N * DK * 4;
    float* out = (float*)d_out;

    const int tb = 256;

    if (ws_size >= need) {
        const int total  = N * 8;            // one thread per uint4 now
        const int prep_n = (E > total) ? E : total;
        prep_kernel<<<(prep_n + tb - 1) / tb, tb, 0, stream>>>(
            dst, (const float4*)Km, (const float4*)Vm, E, N,
            row_ptr, (uint4*)KV);
        const int grid = (N + 15) / 16;     // 16 nodes per block, 4 per wave
        gat_fused_kernel<<<grid, 256, 0, stream>>>(X, (const uint4*)KV, Wo, bo,
                                                   src, row_ptr, out, N);
    } else {
        build_row_ptr_kernel<<<(E + tb - 1) / tb, tb, 0, stream>>>(dst, E, N, row_ptr);
        const int grid = (N + 3) / 4;
        gat_node_f32_kernel<<<grid, 256, 0, stream>>>(X, Km, Vm, Wo, bo,
                                                      src, row_ptr, out, N);
    }
}